// Round 1
// baseline (681.124 us; speedup 1.0000x reference)
//
#include <hip/hip_runtime.h>
#include <hip/hip_bf16.h>

// Problem constants
// B = 512, SHAPE = (64,64,64), RANKS = (8,8,8), SEP = 4
// x:       [512, 64,64,64] f32   (d_in[0], 134217728 elems)
// core:    [8,8,8]        f32    (d_in[1], 512 elems)
// factors: [4, 3, 64, 8]  f32    (d_in[2], 6144 elems)
// out:     [512]          f32

// ---------------------------------------------------------------------------
// Kernel 1: expand T[i,j,k] = sum_s sum_abc core[a,b,c] U1_s[i,a] U2_s[j,b] U3_s[k,c]
// One block per i (64 blocks, 256 threads). Mode-product chain per term s:
//   c1[b,c] = sum_a core[a,b,c] * U1[i,a]        (64 vals, threads 0..63)
//   c2[j,c] = sum_b U2[j,b] * c1[b,c]            (512 vals, 2/thread)
//   T[i,j,k] += sum_c U3[k,c] * c2[j,c]          (4096 vals, 16/thread)
// u3 staged in LDS with stride 9 (8 would alias to 4 banks -> 16-way conflict).
// ---------------------------------------------------------------------------
__global__ __launch_bounds__(256) void tucker_expand_kernel(
    const float* __restrict__ core,
    const float* __restrict__ factors,
    float* __restrict__ T) {
  const int i = blockIdx.x;   // 0..63
  const int t = threadIdx.x;  // 0..255

  __shared__ float core_s[512];   // [a*64 + b*8 + c]
  __shared__ float c1[64];        // [b*8 + c]
  __shared__ float c2[512];       // [j*8 + c]
  __shared__ float u3[64 * 9];    // [k*9 + c], padded stride

  core_s[t]       = core[t];
  core_s[t + 256] = core[t + 256];

  float tacc[16];
#pragma unroll
  for (int m = 0; m < 16; ++m) tacc[m] = 0.f;

  for (int s = 0; s < 4; ++s) {
    // stage U3_s rows into padded LDS
    {
      const float* U3 = factors + ((s * 3 + 2) * 64) * 8;
      int e0 = t, e1 = t + 256;
      u3[(e0 >> 3) * 9 + (e0 & 7)] = U3[e0];
      u3[(e1 >> 3) * 9 + (e1 & 7)] = U3[e1];
    }
    __syncthreads();  // also covers core_s on s==0

    // c1
    if (t < 64) {
      const float* U1row = factors + ((s * 3 + 0) * 64 + i) * 8;
      float v = 0.f;
#pragma unroll
      for (int a = 0; a < 8; ++a) v += core_s[a * 64 + t] * U1row[a];
      c1[t] = v;
    }
    __syncthreads();

    // c2
    {
      const float* U2 = factors + ((s * 3 + 1) * 64) * 8;
#pragma unroll
      for (int rep = 0; rep < 2; ++rep) {
        int e = t + rep * 256;
        int j = e >> 3, c = e & 7;
        float v = 0.f;
#pragma unroll
        for (int b = 0; b < 8; ++b) v += U2[j * 8 + b] * c1[b * 8 + c];
        c2[e] = v;
      }
    }
    __syncthreads();

    // accumulate the 4096-element slice, 16 elems/thread, coalesced e = m*256+t
#pragma unroll
    for (int m = 0; m < 16; ++m) {
      int e = m * 256 + t;
      int j = e >> 6, k = e & 63;
      float v = 0.f;
#pragma unroll
      for (int c = 0; c < 8; ++c) v += u3[k * 9 + c] * c2[j * 8 + c];
      tacc[m] += v;
    }
    __syncthreads();  // protect LDS before next term overwrites
  }

#pragma unroll
  for (int m = 0; m < 16; ++m) T[i * 4096 + m * 256 + t] = tacc[m];
}

// ---------------------------------------------------------------------------
// Kernel 2: partial dot products. 4096 blocks = 512 batches x 8 chunks.
// Each block reduces 32768 floats (128 KiB of x) with float4 loads.
// Deterministic: one partial per block, no atomics.
// ---------------------------------------------------------------------------
__global__ __launch_bounds__(256) void dot_partial_kernel(
    const float* __restrict__ x,
    const float* __restrict__ T,
    float* __restrict__ partials) {
  const int blk = blockIdx.x;
  const int b = blk & 511;         // batch
  const int chunk = blk >> 9;      // 0..7
  const int t = threadIdx.x;

  const float4* x4 = reinterpret_cast<const float4*>(
      x + (size_t)b * 262144 + (size_t)chunk * 32768);
  const float4* t4 = reinterpret_cast<const float4*>(T + (size_t)chunk * 32768);

  float a0 = 0.f, a1 = 0.f, a2 = 0.f, a3 = 0.f;
#pragma unroll 4
  for (int i = 0; i < 32; ++i) {
    int idx = i * 256 + t;
    float4 xv = x4[idx];
    float4 tv = t4[idx];
    a0 += xv.x * tv.x;
    a1 += xv.y * tv.y;
    a2 += xv.z * tv.z;
    a3 += xv.w * tv.w;
  }
  float sum = (a0 + a1) + (a2 + a3);

  // wave-64 reduce
#pragma unroll
  for (int off = 32; off > 0; off >>= 1) sum += __shfl_down(sum, off, 64);

  __shared__ float wsum[4];
  int wave = t >> 6, lane = t & 63;
  if (lane == 0) wsum[wave] = sum;
  __syncthreads();
  if (t == 0) {
    partials[(size_t)chunk * 512 + b] = (wsum[0] + wsum[1]) + (wsum[2] + wsum[3]);
  }
}

// ---------------------------------------------------------------------------
// Kernel 3: out[b] = sum_chunk partials[chunk, b]
// ---------------------------------------------------------------------------
__global__ void reduce_kernel(const float* __restrict__ partials,
                              float* __restrict__ out) {
  int b = blockIdx.x * blockDim.x + threadIdx.x;
  if (b < 512) {
    float s = 0.f;
#pragma unroll
    for (int c = 0; c < 8; ++c) s += partials[c * 512 + b];
    out[b] = s;
  }
}

extern "C" void kernel_launch(void* const* d_in, const int* in_sizes, int n_in,
                              void* d_out, int out_size, void* d_ws, size_t ws_size,
                              hipStream_t stream) {
  const float* x       = (const float*)d_in[0];
  const float* core    = (const float*)d_in[1];
  const float* factors = (const float*)d_in[2];
  float* out = (float*)d_out;

  // workspace layout: T (262144 f32 = 1 MiB) | partials (4096 f32)
  float* T        = (float*)d_ws;
  float* partials = T + 262144;

  tucker_expand_kernel<<<64, 256, 0, stream>>>(core, factors, T);
  dot_partial_kernel<<<4096, 256, 0, stream>>>(x, T, partials);
  reduce_kernel<<<1, 512, 0, stream>>>(partials, out);
}

// Round 2
// 668.955 us; speedup vs baseline: 1.0182x; 1.0182x over previous
//
#include <hip/hip_runtime.h>
#include <hip/hip_bf16.h>

// Problem constants
// B = 512, SHAPE = (64,64,64), RANKS = (8,8,8), SEP = 4
// x:       [512, 64,64,64] f32   (d_in[0], 134217728 elems)
// core:    [8,8,8]        f32    (d_in[1], 512 elems)
// factors: [4, 3, 64, 8]  f32    (d_in[2], 6144 elems)
// out:     [512]          f32

typedef float fvec4 __attribute__((ext_vector_type(4)));

// ---------------------------------------------------------------------------
// Kernel 1: expand T[i,j,k] = sum_s sum_abc core[a,b,c] U1_s[i,a] U2_s[j,b] U3_s[k,c]
// One block per i (64 blocks, 256 threads). Mode-product chain per term s.
// Block 0 additionally zero-inits d_out (it is poisoned to 0xAA by the
// harness; the dot kernel accumulates into it with atomics).
// ---------------------------------------------------------------------------
__global__ __launch_bounds__(256) void tucker_expand_kernel(
    const float* __restrict__ core,
    const float* __restrict__ factors,
    float* __restrict__ T,
    float* __restrict__ out) {
  const int i = blockIdx.x;   // 0..63
  const int t = threadIdx.x;  // 0..255

  if (i == 0) {               // zero d_out (512 floats) for the atomic kernel
    out[t] = 0.f;
    out[t + 256] = 0.f;
  }

  __shared__ float core_s[512];   // [a*64 + b*8 + c]
  __shared__ float c1[64];        // [b*8 + c]
  __shared__ float c2[512];       // [j*8 + c]
  __shared__ float u3[64 * 9];    // [k*9 + c], padded stride kills 4-bank alias

  core_s[t]       = core[t];
  core_s[t + 256] = core[t + 256];

  float tacc[16];
#pragma unroll
  for (int m = 0; m < 16; ++m) tacc[m] = 0.f;

  for (int s = 0; s < 4; ++s) {
    {
      const float* U3 = factors + ((s * 3 + 2) * 64) * 8;
      int e0 = t, e1 = t + 256;
      u3[(e0 >> 3) * 9 + (e0 & 7)] = U3[e0];
      u3[(e1 >> 3) * 9 + (e1 & 7)] = U3[e1];
    }
    __syncthreads();  // also covers core_s on s==0

    if (t < 64) {  // c1[b*8+c] = sum_a core[a,b,c] * U1[i,a]
      const float* U1row = factors + ((s * 3 + 0) * 64 + i) * 8;
      float v = 0.f;
#pragma unroll
      for (int a = 0; a < 8; ++a) v += core_s[a * 64 + t] * U1row[a];
      c1[t] = v;
    }
    __syncthreads();

    {  // c2[j*8+c] = sum_b U2[j,b] * c1[b*8+c]
      const float* U2 = factors + ((s * 3 + 1) * 64) * 8;
#pragma unroll
      for (int rep = 0; rep < 2; ++rep) {
        int e = t + rep * 256;
        int j = e >> 3, c = e & 7;
        float v = 0.f;
#pragma unroll
        for (int b = 0; b < 8; ++b) v += U2[j * 8 + b] * c1[b * 8 + c];
        c2[e] = v;
      }
    }
    __syncthreads();

#pragma unroll
    for (int m = 0; m < 16; ++m) {  // T slice accumulate, coalesced
      int e = m * 256 + t;
      int j = e >> 6, k = e & 63;
      float v = 0.f;
#pragma unroll
      for (int c = 0; c < 8; ++c) v += u3[k * 9 + c] * c2[j * 8 + c];
      tacc[m] += v;
    }
    __syncthreads();
  }

#pragma unroll
  for (int m = 0; m < 16; ++m) T[i * 4096 + m * 256 + t] = tacc[m];
}

// ---------------------------------------------------------------------------
// Kernel 2: dot + reduce. 4096 blocks = 512 batches x 8 chunks.
//   chunk = blk & 7  -> consecutive blocks round-robin across XCDs, so each
//                       T-chunk (128 KiB) stays hot in exactly one XCD L2.
//   x loads are NON-TEMPORAL (read exactly once) so streaming x does not
//   evict T from L2.
// One fp32 atomicAdd per block into d_out (zeroed by kernel 1); with 8 adds
// per element, ordering noise is ~ulp — threshold is 1587.
// ---------------------------------------------------------------------------
__global__ __launch_bounds__(256) void dot_partial_kernel(
    const float* __restrict__ x,
    const float* __restrict__ T,
    float* __restrict__ out) {
  const int blk = blockIdx.x;
  const int chunk = blk & 7;       // 0..7 -> XCD-affine
  const int b = blk >> 3;          // batch 0..511
  const int t = threadIdx.x;

  const fvec4* x4 = reinterpret_cast<const fvec4*>(
      x + (size_t)b * 262144 + (size_t)chunk * 32768);
  const fvec4* t4 = reinterpret_cast<const fvec4*>(T + (size_t)chunk * 32768);

  float a0 = 0.f, a1 = 0.f, a2 = 0.f, a3 = 0.f;
#pragma unroll 8
  for (int i = 0; i < 32; ++i) {
    int idx = i * 256 + t;
    fvec4 xv = __builtin_nontemporal_load(x4 + idx);  // streaming: don't cache
    fvec4 tv = t4[idx];                               // reused: keep in L2
    a0 += xv.x * tv.x;
    a1 += xv.y * tv.y;
    a2 += xv.z * tv.z;
    a3 += xv.w * tv.w;
  }
  float sum = (a0 + a1) + (a2 + a3);

  // wave-64 butterfly
#pragma unroll
  for (int off = 32; off > 0; off >>= 1) sum += __shfl_down(sum, off, 64);

  __shared__ float wsum[4];
  int wave = t >> 6, lane = t & 63;
  if (lane == 0) wsum[wave] = sum;
  __syncthreads();
  if (t == 0) {
    atomicAdd(&out[b], (wsum[0] + wsum[1]) + (wsum[2] + wsum[3]));
  }
}

extern "C" void kernel_launch(void* const* d_in, const int* in_sizes, int n_in,
                              void* d_out, int out_size, void* d_ws, size_t ws_size,
                              hipStream_t stream) {
  const float* x       = (const float*)d_in[0];
  const float* core    = (const float*)d_in[1];
  const float* factors = (const float*)d_in[2];
  float* out = (float*)d_out;

  float* T = (float*)d_ws;  // 262144 f32 = 1 MiB

  tucker_expand_kernel<<<64, 256, 0, stream>>>(core, factors, T, out);
  dot_partial_kernel<<<4096, 256, 0, stream>>>(x, T, out);
}

// Round 3
// 659.388 us; speedup vs baseline: 1.0330x; 1.0145x over previous
//
#include <hip/hip_runtime.h>
#include <hip/hip_bf16.h>

// Problem constants
// B = 512, SHAPE = (64,64,64), RANKS = (8,8,8), SEP = 4
// x:       [512, 64,64,64] f32   (d_in[0], 134217728 elems)
// core:    [8,8,8]        f32    (d_in[1], 512 elems)
// factors: [4, 3, 64, 8]  f32    (d_in[2], 6144 elems)
// out:     [512]          f32

typedef float fvec4 __attribute__((ext_vector_type(4)));

// ---------------------------------------------------------------------------
// Kernel 1: expand T[i,j,k] = sum_s sum_abc core[a,b,c] U1_s[i,a] U2_s[j,b] U3_s[k,c]
// One block per i (64 blocks, 256 threads). Mode-product chain per term s.
// ---------------------------------------------------------------------------
__global__ __launch_bounds__(256) void tucker_expand_kernel(
    const float* __restrict__ core,
    const float* __restrict__ factors,
    float* __restrict__ T) {
  const int i = blockIdx.x;   // 0..63
  const int t = threadIdx.x;  // 0..255

  __shared__ float core_s[512];   // [a*64 + b*8 + c]
  __shared__ float c1[64];        // [b*8 + c]
  __shared__ float c2[512];       // [j*8 + c]
  __shared__ float u3[64 * 9];    // [k*9 + c], padded stride kills 4-bank alias

  core_s[t]       = core[t];
  core_s[t + 256] = core[t + 256];

  float tacc[16];
#pragma unroll
  for (int m = 0; m < 16; ++m) tacc[m] = 0.f;

  for (int s = 0; s < 4; ++s) {
    {
      const float* U3 = factors + ((s * 3 + 2) * 64) * 8;
      int e0 = t, e1 = t + 256;
      u3[(e0 >> 3) * 9 + (e0 & 7)] = U3[e0];
      u3[(e1 >> 3) * 9 + (e1 & 7)] = U3[e1];
    }
    __syncthreads();  // also covers core_s on s==0

    if (t < 64) {  // c1[b*8+c] = sum_a core[a,b,c] * U1[i,a]
      const float* U1row = factors + ((s * 3 + 0) * 64 + i) * 8;
      float v = 0.f;
#pragma unroll
      for (int a = 0; a < 8; ++a) v += core_s[a * 64 + t] * U1row[a];
      c1[t] = v;
    }
    __syncthreads();

    {  // c2[j*8+c] = sum_b U2[j,b] * c1[b*8+c]
      const float* U2 = factors + ((s * 3 + 1) * 64) * 8;
#pragma unroll
      for (int rep = 0; rep < 2; ++rep) {
        int e = t + rep * 256;
        int j = e >> 3, c = e & 7;
        float v = 0.f;
#pragma unroll
        for (int b = 0; b < 8; ++b) v += U2[j * 8 + b] * c1[b * 8 + c];
        c2[e] = v;
      }
    }
    __syncthreads();

#pragma unroll
    for (int m = 0; m < 16; ++m) {  // T slice accumulate, coalesced
      int e = m * 256 + t;
      int j = e >> 6, k = e & 63;
      float v = 0.f;
#pragma unroll
      for (int c = 0; c < 8; ++c) v += u3[k * 9 + c] * c2[j * 8 + c];
      tacc[m] += v;
    }
    __syncthreads();
  }

#pragma unroll
  for (int m = 0; m < 16; ++m) T[i * 4096 + m * 256 + t] = tacc[m];
}

// ---------------------------------------------------------------------------
// Kernel 2: one block per batch. 512 blocks x 1024 threads.
//   __launch_bounds__(1024, 8): caps VGPR at 64 -> 2 blocks/CU -> 32 waves/CU
//   (full occupancy). Each block streams its 1 MiB x-batch with NT float4
//   loads (x read exactly once -> don't pollute L2); T (1 MiB) stays
//   L2-resident per XCD. One reduction + one direct store per block:
//   no atomics, no d_out pre-zeroing, deterministic.
// ---------------------------------------------------------------------------
__global__ __launch_bounds__(1024, 8) void dot_kernel(
    const float* __restrict__ x,
    const float* __restrict__ T,
    float* __restrict__ out) {
  const int b = blockIdx.x;   // batch 0..511
  const int t = threadIdx.x;  // 0..1023

  const fvec4* x4 = reinterpret_cast<const fvec4*>(x + (size_t)b * 262144);
  const fvec4* t4 = reinterpret_cast<const fvec4*>(T);

  float a0 = 0.f, a1 = 0.f, a2 = 0.f, a3 = 0.f;
#pragma unroll 4
  for (int i = 0; i < 64; ++i) {
    int idx = i * 1024 + t;
    fvec4 xv = __builtin_nontemporal_load(x4 + idx);  // streaming
    fvec4 tv = t4[idx];                               // L2-resident
    a0 += xv.x * tv.x;
    a1 += xv.y * tv.y;
    a2 += xv.z * tv.z;
    a3 += xv.w * tv.w;
  }
  float sum = (a0 + a1) + (a2 + a3);

  // wave-64 butterfly
#pragma unroll
  for (int off = 32; off > 0; off >>= 1) sum += __shfl_down(sum, off, 64);

  __shared__ float wsum[16];
  const int wave = t >> 6, lane = t & 63;
  if (lane == 0) wsum[wave] = sum;
  __syncthreads();
  if (wave == 0) {
    float v = (lane < 16) ? wsum[lane] : 0.f;
    v += __shfl_down(v, 8, 64);
    v += __shfl_down(v, 4, 64);
    v += __shfl_down(v, 2, 64);
    v += __shfl_down(v, 1, 64);
    if (lane == 0) out[b] = v;
  }
}

extern "C" void kernel_launch(void* const* d_in, const int* in_sizes, int n_in,
                              void* d_out, int out_size, void* d_ws, size_t ws_size,
                              hipStream_t stream) {
  const float* x       = (const float*)d_in[0];
  const float* core    = (const float*)d_in[1];
  const float* factors = (const float*)d_in[2];
  float* out = (float*)d_out;

  float* T = (float*)d_ws;  // 262144 f32 = 1 MiB

  tucker_expand_kernel<<<64, 256, 0, stream>>>(core, factors, T);
  dot_kernel<<<512, 1024, 0, stream>>>(x, T, out);
}